// Round 7
// baseline (230.001 us; speedup 1.0000x reference)
//
#include <hip/hip_runtime.h>
#include <hip/hip_bf16.h>
#include <math.h>

#define NPTS 4096
#define FIN 512
#define FOUT 64
#define NG 44

typedef __attribute__((ext_vector_type(8))) short bf16x8;
typedef __attribute__((ext_vector_type(4))) float f32x4;

static __device__ __forceinline__ unsigned short bfbits(float x) {
  __hip_bfloat16 b = __float2bfloat16(x);
  return *reinterpret_cast<unsigned short*>(&b);
}

static __device__ __forceinline__ float wsum64(float v) {
  #pragma unroll
  for (int mm = 1; mm < 64; mm <<= 1) v += __shfl_xor(v, mm);
  return v;
}

// ---------------- prep: bf16 copy of h, row norms, init m1; blocks>=1024: W -> WbT ----------------
__global__ __launch_bounds__(256) void k_prep(const float* __restrict__ h,
    const float* __restrict__ W, __hip_bfloat16* __restrict__ xb,
    float* __restrict__ sq, int* __restrict__ m1, __hip_bfloat16* __restrict__ WbT) {
  int bid = blockIdx.x, t = threadIdx.x;
  if (bid >= 1024) {
    int base = (bid - 1024) * 16384;
    for (int rep = 0; rep < 64; ++rep) {
      int e = base + rep * 256 + t;
      int n = e >> 9, k = e & 511;
      WbT[e] = __float2bfloat16(W[k * FOUT + n]);  // WbT[n][k], coalesced write
    }
    return;
  }
  int lane = t & 63, wid = t >> 6;
  int row = bid * 4 + wid;
  const float4* hr = (const float4*)(h + (size_t)row * FIN);
  float4 a = hr[lane], b = hr[64 + lane];
  ushort4 pa = { bfbits(a.x), bfbits(a.y), bfbits(a.z), bfbits(a.w) };
  ushort4 pb = { bfbits(b.x), bfbits(b.y), bfbits(b.z), bfbits(b.w) };
  *(ushort4*)(xb + (size_t)row * FIN + 4 * lane) = pa;
  *(ushort4*)(xb + (size_t)row * FIN + 256 + 4 * lane) = pb;
  float s = a.x*a.x + a.y*a.y + a.z*a.z + a.w*a.w
          + b.x*b.x + b.y*b.y + b.z*b.z + b.w*b.w;
  s = wsum64(s);
  if (lane == 0) { sq[row] = s; m1[row] = 0x7F800000; }
}

// ---------------- gram role (256 active threads; waves 4-7 barrier-only) ----------------
__device__ __forceinline__ void gram_role(const __hip_bfloat16* __restrict__ xb,
    const float* __restrict__ sq, int* __restrict__ m1, int gb, char* smem) {
  bool act = threadIdx.x < 256;
  int tid = threadIdx.x;
  int lane = tid & 63, wid = tid >> 6;
  int b = gb, I = 0;
  while (b >= 32 - I) { b -= 32 - I; ++I; }
  int J = I + b;
  char* As = smem;
  char* Bs = smem + 16384;

  int R0 = I * 128, C0 = J * 128;
  int rowBase = (wid >> 1) * 64;
  int colBase = (wid & 1) * 64;
  int lrow = lane & 15, hi = lane >> 4, rsub = hi * 4;

  f32x4 acc[4][4];
  #pragma unroll
  for (int p = 0; p < 4; ++p)
    #pragma unroll
    for (int q = 0; q < 4; ++q)
      acc[p][q] = (f32x4){0.f, 0.f, 0.f, 0.f};

  int srow = lane >> 3;
  int scol = ((lane & 7) ^ srow) * 8;
  const __hip_bfloat16* gA = xb + (size_t)(R0 + (wid & 3) * 32 + srow) * FIN + scol;
  const __hip_bfloat16* gB = xb + (size_t)(C0 + (wid & 3) * 32 + srow) * FIN + scol;
  char* lA = As + (wid & 3) * 4096;
  char* lB = Bs + (wid & 3) * 4096;
  int rdswz = (lrow & 7) << 4;

  for (int kt = 0; kt < 8; ++kt) {
    int K0 = kt * 64;
    if (act) {
      #pragma unroll
      for (int j = 0; j < 4; ++j) {
        __builtin_amdgcn_global_load_lds(
            (const __attribute__((address_space(1))) unsigned int*)(gA + (size_t)(8 * j) * FIN + K0),
            (__attribute__((address_space(3))) unsigned int*)(lA + j * 1024), 16, 0, 0);
        __builtin_amdgcn_global_load_lds(
            (const __attribute__((address_space(1))) unsigned int*)(gB + (size_t)(8 * j) * FIN + K0),
            (__attribute__((address_space(3))) unsigned int*)(lB + j * 1024), 16, 0, 0);
      }
    }
    __syncthreads();
    if (act) {
      #pragma unroll
      for (int s = 0; s < 2; ++s) {
        int k0b = s * 64;
        bf16x8 av[4], bw[4];
        #pragma unroll
        for (int f = 0; f < 4; ++f) {
          int arow = rowBase + f * 16 + lrow;
          av[f] = *(const bf16x8*)(As + arow * 128 + ((k0b + hi * 16) ^ rdswz));
          int brow = colBase + f * 16 + lrow;
          bw[f] = *(const bf16x8*)(Bs + brow * 128 + ((k0b + hi * 16) ^ rdswz));
        }
        #pragma unroll
        for (int fi = 0; fi < 4; ++fi)
          #pragma unroll
          for (int fj = 0; fj < 4; ++fj)
            acc[fi][fj] = __builtin_amdgcn_mfma_f32_16x16x32_bf16(av[fi], bw[fj], acc[fi][fj], 0, 0, 0);
      }
    }
    __syncthreads();
  }
  if (!act) return;

  int rowBaseG = R0 + rowBase, colBaseG = C0 + colBase;
  float sqr[16], sqc4[4];
  #pragma unroll
  for (int fi = 0; fi < 4; ++fi)
    #pragma unroll
    for (int rg = 0; rg < 4; ++rg)
      sqr[fi * 4 + rg] = sq[rowBaseG + fi * 16 + rsub + rg];
  #pragma unroll
  for (int fj = 0; fj < 4; ++fj) sqc4[fj] = sq[colBaseG + fj * 16 + lrow];

  float rmin[16], cmin[4];
  #pragma unroll
  for (int q = 0; q < 16; ++q) rmin[q] = INFINITY;
  #pragma unroll
  for (int q = 0; q < 4; ++q) cmin[q] = INFINITY;

  #pragma unroll
  for (int fi = 0; fi < 4; ++fi)
    #pragma unroll
    for (int fj = 0; fj < 4; ++fj)
      #pragma unroll
      for (int rg = 0; rg < 4; ++rg) {
        int r = rowBaseG + fi * 16 + rsub + rg;
        int c = colBaseG + fj * 16 + lrow;
        float d2 = sqr[fi * 4 + rg] + sqc4[fj] - 2.f * acc[fi][fj][rg];
        if (r == c) d2 = INFINITY;
        rmin[fi * 4 + rg] = fminf(rmin[fi * 4 + rg], d2);
        cmin[fj] = fminf(cmin[fj], d2);
      }

  #pragma unroll
  for (int mm = 1; mm < 16; mm <<= 1) {
    #pragma unroll
    for (int q = 0; q < 16; ++q) rmin[q] = fminf(rmin[q], __shfl_xor(rmin[q], mm));
  }
  if ((lane & 15) == 0) {
    #pragma unroll
    for (int q = 0; q < 16; ++q) {
      int r = rowBaseG + (q >> 2) * 16 + rsub + (q & 3);
      atomicMin(&m1[r], __float_as_int(rmin[q]));
    }
  }
  if (I != J) {
    #pragma unroll
    for (int mm = 16; mm < 64; mm <<= 1) {
      #pragma unroll
      for (int q = 0; q < 4; ++q) cmin[q] = fminf(cmin[q], __shfl_xor(cmin[q], mm));
    }
    if ((lane >> 4) == 0) {
      #pragma unroll
      for (int q = 0; q < 4; ++q)
        atomicMin(&m1[colBaseG + q * 16 + lane], __float_as_int(cmin[q]));
    }
  }
}

// ---------------- Wh = xb @ WbT^T via MFMA (32 blocks x 512) ----------------
__device__ __forceinline__ void whmm_role(const __hip_bfloat16* __restrict__ xb,
    const __hip_bfloat16* __restrict__ WbT, float* __restrict__ Wh, int wb) {
  int t = threadIdx.x, lane = t & 63, wid = t >> 6;
  int r16 = lane & 15, hi = lane >> 4;
  int rbase = wb * 128 + wid * 16;
  f32x4 acc[4];
  #pragma unroll
  for (int fn = 0; fn < 4; ++fn) acc[fn] = (f32x4){0.f, 0.f, 0.f, 0.f};
  const __hip_bfloat16* aP = xb + (size_t)(rbase + r16) * FIN + hi * 8;
  const __hip_bfloat16* bP[4];
  #pragma unroll
  for (int fn = 0; fn < 4; ++fn)
    bP[fn] = WbT + (size_t)(fn * 16 + r16) * FIN + hi * 8;
  #pragma unroll
  for (int kk = 0; kk < 16; ++kk) {
    bf16x8 a = *(const bf16x8*)(aP + kk * 32);
    #pragma unroll
    for (int fn = 0; fn < 4; ++fn) {
      bf16x8 bw = *(const bf16x8*)(bP[fn] + kk * 32);
      acc[fn] = __builtin_amdgcn_mfma_f32_16x16x32_bf16(a, bw, acc[fn], 0, 0, 0);
    }
  }
  #pragma unroll
  for (int fn = 0; fn < 4; ++fn)
    #pragma unroll
    for (int q = 0; q < 4; ++q)
      Wh[(size_t)(rbase + hi * 4 + q) * FOUT + fn * 16 + r16] = acc[fn][q];
}

// ---------------- transpose Wh -> WhbT role (256 active threads) ----------------
__device__ __forceinline__ void tr_role(const float* __restrict__ Wh,
    __hip_bfloat16* __restrict__ WhbT, int trb, char* smem) {
  __hip_bfloat16 (*tT)[264] = (__hip_bfloat16(*)[264])smem;
  int t = threadIdx.x;
  bool act = t < 256;
  int kbase = trb * 256;
  if (act) {
    for (int rep = 0; rep < 64; ++rep) {
      int idx = t + rep * 256;
      int k = idx >> 6, n = idx & 63;
      tT[n][k] = __float2bfloat16(Wh[(size_t)(kbase + k) * FOUT + n]);
    }
  }
  __syncthreads();
  if (act) {
    int n = t >> 2, kq = t & 3;
    #pragma unroll
    for (int rep = 0; rep < 8; ++rep) {
      int kk = kq * 64 + rep * 8;
      bf16x8 v = *(const bf16x8*)&tT[n][kk];
      *(bf16x8*)(WhbT + (size_t)n * NPTS + kbase + kk) = v;
    }
  }
}

// ---------------- row loader ----------------
__device__ __forceinline__ void load_rows(const float* __restrict__ h, int rbase,
    int lane, float x[8][8]) {
  #pragma unroll
  for (int r = 0; r < 8; ++r) {
    const float4* xr = (const float4*)(h + (size_t)(rbase + r) * FIN);
    float4 u0 = xr[2 * lane], u1 = xr[2 * lane + 1];
    x[r][0]=u0.x; x[r][1]=u0.y; x[r][2]=u0.z; x[r][3]=u0.w;
    x[r][4]=u1.x; x[r][5]=u1.y; x[r][6]=u1.z; x[r][7]=u1.w;
  }
}

// ---------------- Lloyd assign (8 rows/wave, batched reduces) ----------------
__device__ __forceinline__ void lloyd_assign(const float* __restrict__ h,
    const float* __restrict__ sq, const float* cents, float* wsum, float* wcnt,
    float* __restrict__ psOut, float* __restrict__ pcOut) {
  int t = threadIdx.x, lane = t & 63, wid = t >> 6, b = blockIdx.x;
  float c0r[8], c1r[8], c2r[8];
  {
    float4 u;
    u = *(const float4*)&cents[8 * lane];          c0r[0]=u.x;c0r[1]=u.y;c0r[2]=u.z;c0r[3]=u.w;
    u = *(const float4*)&cents[8 * lane + 4];      c0r[4]=u.x;c0r[5]=u.y;c0r[6]=u.z;c0r[7]=u.w;
    u = *(const float4*)&cents[512 + 8 * lane];    c1r[0]=u.x;c1r[1]=u.y;c1r[2]=u.z;c1r[3]=u.w;
    u = *(const float4*)&cents[512 + 8 * lane + 4];c1r[4]=u.x;c1r[5]=u.y;c1r[6]=u.z;c1r[7]=u.w;
    u = *(const float4*)&cents[1024 + 8 * lane];   c2r[0]=u.x;c2r[1]=u.y;c2r[2]=u.z;c2r[3]=u.w;
    u = *(const float4*)&cents[1024 + 8*lane + 4]; c2r[4]=u.x;c2r[5]=u.y;c2r[6]=u.z;c2r[7]=u.w;
  }
  float s0 = 0.f, s1 = 0.f, s2 = 0.f;
  #pragma unroll
  for (int q = 0; q < 8; ++q) {
    s0 = fmaf(c0r[q], c0r[q], s0); s1 = fmaf(c1r[q], c1r[q], s1); s2 = fmaf(c2r[q], c2r[q], s2);
  }
  #pragma unroll
  for (int mm = 1; mm < 64; mm <<= 1) {
    s0 += __shfl_xor(s0, mm); s1 += __shfl_xor(s1, mm); s2 += __shfl_xor(s2, mm);
  }
  float sqc0 = s0, sqc1 = s1, sqc2 = s2;

  int rbase = b * 64 + wid * 8;
  float x[8][8];
  load_rows(h, rbase, lane, x);
  float d[8][3];
  #pragma unroll
  for (int r = 0; r < 8; ++r) { d[r][0] = 0.f; d[r][1] = 0.f; d[r][2] = 0.f; }
  #pragma unroll
  for (int r = 0; r < 8; ++r)
    #pragma unroll
    for (int q = 0; q < 8; ++q) {
      d[r][0] = fmaf(x[r][q], c0r[q], d[r][0]);
      d[r][1] = fmaf(x[r][q], c1r[q], d[r][1]);
      d[r][2] = fmaf(x[r][q], c2r[q], d[r][2]);
    }
  #pragma unroll
  for (int mm = 1; mm < 64; mm <<= 1) {
    #pragma unroll
    for (int r = 0; r < 8; ++r) {
      d[r][0] += __shfl_xor(d[r][0], mm);
      d[r][1] += __shfl_xor(d[r][1], mm);
      d[r][2] += __shfl_xor(d[r][2], mm);
    }
  }
  float ps[3][8];
  #pragma unroll
  for (int c = 0; c < 3; ++c)
    #pragma unroll
    for (int q = 0; q < 8; ++q) ps[c][q] = 0.f;
  float cnt0 = 0.f, cnt1 = 0.f, cnt2 = 0.f;
  #pragma unroll
  for (int r = 0; r < 8; ++r) {
    float sr = sq[rbase + r];
    float e0 = sr + sqc0 - 2.f * d[r][0];
    float e1 = sr + sqc1 - 2.f * d[r][1];
    float e2 = sr + sqc2 - 2.f * d[r][2];
    int bc = 0; float bd = e0;
    if (e1 < bd) { bd = e1; bc = 1; }
    if (e2 < bd) { bd = e2; bc = 2; }
    float f0 = bc == 0 ? 1.f : 0.f, f1 = bc == 1 ? 1.f : 0.f, f2 = bc == 2 ? 1.f : 0.f;
    #pragma unroll
    for (int q = 0; q < 8; ++q) {
      ps[0][q] = fmaf(f0, x[r][q], ps[0][q]);
      ps[1][q] = fmaf(f1, x[r][q], ps[1][q]);
      ps[2][q] = fmaf(f2, x[r][q], ps[2][q]);
    }
    cnt0 += f0; cnt1 += f1; cnt2 += f2;
  }
  #pragma unroll
  for (int c = 0; c < 3; ++c) {
    *(float4*)&wsum[wid * 1536 + c * 512 + 8 * lane]     = make_float4(ps[c][0], ps[c][1], ps[c][2], ps[c][3]);
    *(float4*)&wsum[wid * 1536 + c * 512 + 8 * lane + 4] = make_float4(ps[c][4], ps[c][5], ps[c][6], ps[c][7]);
  }
  if (lane == 0) { wcnt[wid * 3 + 0] = cnt0; wcnt[wid * 3 + 1] = cnt1; wcnt[wid * 3 + 2] = cnt2; }
  __syncthreads();
  for (int idx = t; idx < 1536; idx += 512) {
    float s = ((wsum[0 * 1536 + idx] + wsum[1 * 1536 + idx]) + (wsum[2 * 1536 + idx] + wsum[3 * 1536 + idx]))
            + ((wsum[4 * 1536 + idx] + wsum[5 * 1536 + idx]) + (wsum[6 * 1536 + idx] + wsum[7 * 1536 + idx]));
    psOut[(size_t)b * 1536 + idx] = s;
  }
  if (t < 3) {
    float s = 0.f;
    for (int w = 0; w < 8; ++w) s += wcnt[w * 3 + t];
    pcOut[t * 64 + b] = s;   // [c][64]
  }
}

// ---------------- carrier kernel: kmeans role (blocks 0-63) + gram slice + tail role ----------------
// MODE 0: fp0 (+whmm tail). MODE 1: fp1 (+tr tail). MODE 2: lloyd0. MODE 3: lloyd.
template<int MODE>
__global__ __launch_bounds__(512) void k_carrier(
    const float* __restrict__ h, const float* __restrict__ sq,
    const __hip_bfloat16* __restrict__ xb, int* __restrict__ m1,
    const float* __restrict__ t2, float* __restrict__ dkm,
    float* __restrict__ bvA, int* __restrict__ biA,
    float* __restrict__ bvB, int* __restrict__ biB, int* __restrict__ b1s,
    float* __restrict__ tmpart, float* __restrict__ kvp, int* __restrict__ kip,
    const float* __restrict__ psIn, const float* __restrict__ pcIn,
    float* __restrict__ psOut, float* __restrict__ pcOut,
    const __hip_bfloat16* __restrict__ WbT, float* __restrict__ Wh,
    __hip_bfloat16* __restrict__ WhbT, int gramOff) {
  __shared__ __align__(16) char smem[55552];
  int bid = blockIdx.x;
  if (bid >= 64 + NG) {
    if (MODE == 0) whmm_role(xb, WbT, Wh, bid - 64 - NG);
    else           tr_role(Wh, WhbT, bid - 64 - NG, smem);
    return;
  }
  if (bid >= 64) { gram_role(xb, sq, m1, gramOff + bid - 64, smem); return; }

  float* wsum  = (float*)smem;               // 49152 B
  float* cents = (float*)(smem + 49152);     // 6144 B
  float* wcnt  = (float*)(smem + 55296);     // 96 B
  float* misc  = (float*)(smem + 55392);     // 40 floats
  float* rv = misc;
  int*   ri = (int*)(misc + 8);
  int*   sI = (int*)(misc + 16);
  float* cntS = misc + 20;

  int t = threadIdx.x, lane = t & 63, wid = t >> 6, b = bid;

  if (MODE <= 1) {
    // farthest-point passes
    float cr[8];
    int b1 = 0;
    if (MODE == 1) {
      if (wid == 0) {
        float v = bvA[lane]; int i = biA[lane];
        #pragma unroll
        for (int mm = 1; mm < 64; mm <<= 1) {
          float ov = __shfl_xor(v, mm); int oi = __shfl_xor(i, mm);
          if (ov > v || (ov == v && oi < i)) { v = ov; i = oi; }
        }
        if (lane == 0) sI[0] = i;
      }
      __syncthreads();
      b1 = sI[0];
      if (b == 0 && t == 0) b1s[0] = b1;
    }
    {
      const float4* cp = (const float4*)(h + (MODE == 0 ? 0 : (size_t)b1 * FIN));
      float4 u0 = cp[2 * lane], u1 = cp[2 * lane + 1];
      cr[0]=u0.x;cr[1]=u0.y;cr[2]=u0.z;cr[3]=u0.w;cr[4]=u1.x;cr[5]=u1.y;cr[6]=u1.z;cr[7]=u1.w;
    }
    float s0 = 0.f;
    #pragma unroll
    for (int q = 0; q < 8; ++q) s0 = fmaf(cr[q], cr[q], s0);
    float sqc0 = wsum64(s0);
    int rbase = b * 64 + wid * 8;
    float x[8][8];
    load_rows(h, rbase, lane, x);
    float dd[8];
    #pragma unroll
    for (int r = 0; r < 8; ++r) dd[r] = 0.f;
    #pragma unroll
    for (int r = 0; r < 8; ++r)
      #pragma unroll
      for (int q = 0; q < 8; ++q) dd[r] = fmaf(x[r][q], cr[q], dd[r]);
    #pragma unroll
    for (int mm = 1; mm < 64; mm <<= 1) {
      #pragma unroll
      for (int r = 0; r < 8; ++r) dd[r] += __shfl_xor(dd[r], mm);
    }
    float bv = -1.f; int bi = 0;
    #pragma unroll
    for (int r = 0; r < 8; ++r) {
      int row = rbase + r;
      float d = sq[row] + sqc0 - 2.f * dd[r];
      if (MODE == 1) d = fminf(d, dkm[row]);
      if (lane == 0) dkm[row] = d;
      if (d > bv) { bv = d; bi = row; }
    }
    if (lane == 0) { rv[wid] = bv; ri[wid] = bi; }
    if (MODE == 0) {
      // side partials: tm / kstar
      if (wid == 1) {
        #pragma unroll
        for (int c = 0; c < 3; ++c) {
          float m = fabsf(t2[c * NPTS + b * 64 + lane]);
          #pragma unroll
          for (int mm = 1; mm < 64; mm <<= 1) m = fmaxf(m, __shfl_xor(m, mm));
          if (lane == 0) tmpart[b * 3 + c] = m;
        }
      } else if (wid == 2) {
        int k = b * 64 + lane;
        float v = t2[k] + t2[NPTS + k] + t2[2 * NPTS + k];
        int ki = k;
        #pragma unroll
        for (int mm = 1; mm < 64; mm <<= 1) {
          float ov = __shfl_xor(v, mm); int oi = __shfl_xor(ki, mm);
          if (ov < v || (ov == v && oi < ki)) { v = ov; ki = oi; }
        }
        if (lane == 0) { kvp[b] = v; kip[b] = ki; }
      }
    }
    __syncthreads();
    if (t == 0) {
      float vv = rv[0]; int ii = ri[0];
      for (int w = 1; w < 8; ++w)
        if (rv[w] > vv || (rv[w] == vv && ri[w] < ii)) { vv = rv[w]; ii = ri[w]; }
      if (MODE == 0) { bvA[b] = vv; biA[b] = ii; }
      else           { bvB[b] = vv; biB[b] = ii; }
    }
    return;
  }

  if (MODE == 2) {
    // init centers from (h[0], h[b1], h[b2]); b2 = argmax of bvB
    if (wid == 0) {
      float v = bvB[lane]; int i = biB[lane];
      #pragma unroll
      for (int mm = 1; mm < 64; mm <<= 1) {
        float ov = __shfl_xor(v, mm); int oi = __shfl_xor(i, mm);
        if (ov > v || (ov == v && oi < i)) { v = ov; i = oi; }
      }
      if (lane == 0) sI[0] = i;
    }
    __syncthreads();
    int b1 = b1s[0], b2 = sI[0];
    cents[t]        = h[t];
    cents[512 + t]  = h[(size_t)b1 * FIN + t];
    cents[1024 + t] = h[(size_t)b2 * FIN + t];
    __syncthreads();
    lloyd_assign(h, sq, cents, wsum, wcnt, psOut, pcOut);
    return;
  }

  // MODE 3: reduce partials -> centers, assign
  if (t < 192) {
    float v = pcIn[t];
    v = wsum64(v);
    if ((t & 63) == 0) cntS[t >> 6] = v;
  }
  __syncthreads();
  if (t < 384) {
    const f32x4* P = (const f32x4*)psIn;
    f32x4 a0 = {0,0,0,0}, a1 = {0,0,0,0}, a2 = {0,0,0,0}, a3 = {0,0,0,0};
    #pragma unroll 4
    for (int bq = 0; bq < 64; bq += 4) {
      a0 += P[(bq + 0) * 384 + t];
      a1 += P[(bq + 1) * 384 + t];
      a2 += P[(bq + 2) * 384 + t];
      a3 += P[(bq + 3) * 384 + t];
    }
    f32x4 s = (a0 + a1) + (a2 + a3);
    float cden = fmaxf(cntS[t >> 7], 1.f);
    f32x4 res;
    res[0] = s[0] / cden; res[1] = s[1] / cden; res[2] = s[2] / cden; res[3] = s[3] / cden;
    *(f32x4*)&cents[4 * t] = res;
  }
  __syncthreads();
  lloyd_assign(h, sq, cents, wsum, wcnt, psOut, pcOut);
}

// ---------------- finalize: centers, dc (from m1), d1val, tm/kstar tail ----------------
__global__ __launch_bounds__(512) void k_fin(const float* __restrict__ h,
    const float* __restrict__ sq, const float* __restrict__ psIn, const float* __restrict__ pcIn,
    const int* __restrict__ m1, const float* __restrict__ tmpart,
    const float* __restrict__ kvp, const int* __restrict__ kip,
    const float* __restrict__ Wh, float* __restrict__ d1v,
    float* __restrict__ tmv, float* __restrict__ out) {
  __shared__ float cents[1536];
  __shared__ float cntS[3];
  __shared__ float dcw[8];
  __shared__ int skstar;
  int t = threadIdx.x, lane = t & 63, wid = t >> 6, b = blockIdx.x;
  // dc partial (redundant per block)
  {
    float sdc = 0.f;
    #pragma unroll
    for (int q = 0; q < 8; ++q)
      sdc += sqrtf(fmaxf(__int_as_float(m1[t + 512 * q]), 0.f));
    sdc = wsum64(sdc);
    if (lane == 0) dcw[wid] = sdc;
  }
  if (t < 192) {
    float v = pcIn[t];
    v = wsum64(v);
    if ((t & 63) == 0) cntS[t >> 6] = v;
  }
  __syncthreads();
  if (t < 384) {
    const f32x4* P = (const f32x4*)psIn;
    f32x4 a0 = {0,0,0,0}, a1 = {0,0,0,0}, a2 = {0,0,0,0}, a3 = {0,0,0,0};
    #pragma unroll 4
    for (int bq = 0; bq < 64; bq += 4) {
      a0 += P[(bq + 0) * 384 + t];
      a1 += P[(bq + 1) * 384 + t];
      a2 += P[(bq + 2) * 384 + t];
      a3 += P[(bq + 3) * 384 + t];
    }
    f32x4 s = (a0 + a1) + (a2 + a3);
    float cden = fmaxf(cntS[t >> 7], 1.f);
    f32x4 res;
    res[0] = s[0] / cden; res[1] = s[1] / cden; res[2] = s[2] / cden; res[3] = s[3] / cden;
    *(f32x4*)&cents[4 * t] = res;
  }
  __syncthreads();
  float dcv = (((dcw[0] + dcw[1]) + (dcw[2] + dcw[3])) + ((dcw[4] + dcw[5]) + (dcw[6] + dcw[7])))
            * (1.f / (float)NPTS);
  float c0r[8], c1r[8], c2r[8];
  {
    float4 u;
    u = *(const float4*)&cents[8 * lane];          c0r[0]=u.x;c0r[1]=u.y;c0r[2]=u.z;c0r[3]=u.w;
    u = *(const float4*)&cents[8 * lane + 4];      c0r[4]=u.x;c0r[5]=u.y;c0r[6]=u.z;c0r[7]=u.w;
    u = *(const float4*)&cents[512 + 8 * lane];    c1r[0]=u.x;c1r[1]=u.y;c1r[2]=u.z;c1r[3]=u.w;
    u = *(const float4*)&cents[512 + 8 * lane + 4];c1r[4]=u.x;c1r[5]=u.y;c1r[6]=u.z;c1r[7]=u.w;
    u = *(const float4*)&cents[1024 + 8 * lane];   c2r[0]=u.x;c2r[1]=u.y;c2r[2]=u.z;c2r[3]=u.w;
    u = *(const float4*)&cents[1024 + 8*lane + 4]; c2r[4]=u.x;c2r[5]=u.y;c2r[6]=u.z;c2r[7]=u.w;
  }
  float s0 = 0.f, s1 = 0.f, s2 = 0.f;
  #pragma unroll
  for (int q = 0; q < 8; ++q) {
    s0 = fmaf(c0r[q], c0r[q], s0); s1 = fmaf(c1r[q], c1r[q], s1); s2 = fmaf(c2r[q], c2r[q], s2);
  }
  #pragma unroll
  for (int mm = 1; mm < 64; mm <<= 1) {
    s0 += __shfl_xor(s0, mm); s1 += __shfl_xor(s1, mm); s2 += __shfl_xor(s2, mm);
  }
  float sqc0 = s0, sqc1 = s1, sqc2 = s2;

  int rbase = b * 64 + wid * 8;
  float x[8][8];
  load_rows(h, rbase, lane, x);
  float d[8][3];
  #pragma unroll
  for (int r = 0; r < 8; ++r) { d[r][0] = 0.f; d[r][1] = 0.f; d[r][2] = 0.f; }
  #pragma unroll
  for (int r = 0; r < 8; ++r)
    #pragma unroll
    for (int q = 0; q < 8; ++q) {
      d[r][0] = fmaf(x[r][q], c0r[q], d[r][0]);
      d[r][1] = fmaf(x[r][q], c1r[q], d[r][1]);
      d[r][2] = fmaf(x[r][q], c2r[q], d[r][2]);
    }
  #pragma unroll
  for (int mm = 1; mm < 64; mm <<= 1) {
    #pragma unroll
    for (int r = 0; r < 8; ++r) {
      d[r][0] += __shfl_xor(d[r][0], mm);
      d[r][1] += __shfl_xor(d[r][1], mm);
      d[r][2] += __shfl_xor(d[r][2], mm);
    }
  }
  if (lane == 0) {
    #pragma unroll
    for (int r = 0; r < 8; ++r) {
      int row = rbase + r;
      float sr = sq[row];
      float q0 = sqrtf(fmaxf(sr + sqc0 - 2.f * d[r][0], 0.f));
      float q1 = sqrtf(fmaxf(sr + sqc1 - 2.f * d[r][1], 0.f));
      float q2 = sqrtf(fmaxf(sr + sqc2 - 2.f * d[r][2], 0.f));
      float nr = q1;
      d1v[row * 3 + 0] = (q0 != 0.f) ? (dcv * nr / (q0 * q0)) : 0.f;
      d1v[row * 3 + 1] = (q1 != 0.f) ? (dcv * nr / (q1 * q1)) : 0.f;
      d1v[row * 3 + 2] = (q2 != 0.f) ? (dcv * nr / (q2 * q2)) : 0.f;
    }
  }
  if (b == 0) {
    if (t < 3) {
      float m = 0.f;
      for (int q = 0; q < 64; ++q) m = fmaxf(m, tmpart[q * 3 + t]);
      tmv[t] = m;
    }
    if (wid == 0) {
      float v = kvp[lane]; int i = kip[lane];
      #pragma unroll
      for (int mm = 1; mm < 64; mm <<= 1) {
        float ov = __shfl_xor(v, mm); int oi = __shfl_xor(i, mm);
        if (ov < v || (ov == v && oi < i)) { v = ov; i = oi; }
      }
      if (lane == 0) skstar = i;
    }
    __syncthreads();
    int kstar = skstar;
    if (t < 192) {
      int c = t >> 6, j = t & 63;
      float wv = Wh[(size_t)kstar * FOUT + j];
      out[(size_t)(NPTS + c) * FOUT + j] = wv > 0.f ? wv : expm1f(wv);
    }
  }
}

// ---------------- fused MFMA softmax-numerator @ Wh: 512 thr, waves split K-half ----------------
__global__ __launch_bounds__(512) void k_mainA(const float* __restrict__ t2,
    const __hip_bfloat16* __restrict__ WhbT, const float* __restrict__ d1v,
    const float* __restrict__ tm, float* __restrict__ Vpart, float* __restrict__ Spart) {
  int t = threadIdx.x, lane = t & 63, wid = t >> 6;
  int rb = blockIdx.x & 63, ks = blockIdx.x >> 6;
  int R0 = rb * 64, K0 = ks * 1024;
  __shared__ float t2s[3 * 1024];
  __shared__ float VcS[4][16][68];
  __shared__ float SpS[4][2][16];
  for (int idx = t; idx < 3072; idx += 512) {
    int c = idx >> 10, kl = idx & 1023;
    t2s[idx] = t2[c * NPTS + K0 + kl];
  }
  __syncthreads();
  int r = lane & 15, hi = lane >> 4;
  int rg = wid & 3, kh = wid >> 2;
  int row_g = R0 + rg * 16 + r;
  float a0 = d1v[row_g * 3 + 0], a1 = d1v[row_g * 3 + 1], a2 = d1v[row_g * 3 + 2];
  float M = fmaf(fabsf(a2), tm[2], fmaf(fabsf(a1), tm[1], fabsf(a0) * tm[0]));
  f32x4 acc[4];
  #pragma unroll
  for (int fn = 0; fn < 4; ++fn) acc[fn] = (f32x4){0.f, 0.f, 0.f, 0.f};
  float Sp = 0.f;
  const __hip_bfloat16* bwB[4];
  #pragma unroll
  for (int fn = 0; fn < 4; ++fn)
    bwB[fn] = WhbT + (size_t)(fn * 16 + r) * NPTS + K0 + kh * 512 + hi * 8;

  for (int kst = 0; kst < 16; ++kst) {
    int kb = kh * 512 + kst * 32 + hi * 8;
    f32x4 c0a = *(const f32x4*)&t2s[kb],        c0b = *(const f32x4*)&t2s[kb + 4];
    f32x4 c1a = *(const f32x4*)&t2s[1024 + kb], c1b = *(const f32x4*)&t2s[1024 + kb + 4];
    f32x4 c2a = *(const f32x4*)&t2s[2048 + kb], c2b = *(const f32x4*)&t2s[2048 + kb + 4];
    float pv[8];
    #pragma unroll
    for (int j = 0; j < 4; ++j) {
      float L  = fmaf(a0, c0a[j], fmaf(a1, c1a[j], fmaf(a2, c2a[j], -M)));
      pv[j] = __expf(L);
      float L2 = fmaf(a0, c0b[j], fmaf(a1, c1b[j], fmaf(a2, c2b[j], -M)));
      pv[4 + j] = __expf(L2);
    }
    Sp += ((pv[0] + pv[1]) + (pv[2] + pv[3])) + ((pv[4] + pv[5]) + (pv[6] + pv[7]));
    union { bf16x8 v; __hip_bfloat162 h2[4]; } pa;
    #pragma unroll
    for (int jj = 0; jj < 4; ++jj) {
      float2 f2; f2.x = pv[2 * jj]; f2.y = pv[2 * jj + 1];
      pa.h2[jj] = __float22bfloat162_rn(f2);
    }
    #pragma unroll
    for (int fn = 0; fn < 4; ++fn) {
      bf16x8 bw = *(const bf16x8*)(bwB[fn] + kst * 32);
      acc[fn] = __builtin_amdgcn_mfma_f32_16x16x32_bf16(pa.v, bw, acc[fn], 0, 0, 0);
    }
  }
  Sp += __shfl_xor(Sp, 16);
  Sp += __shfl_xor(Sp, 32);
  if (hi == 0) SpS[rg][kh][r] = Sp;
  if (kh == 0) {
    #pragma unroll
    for (int fn = 0; fn < 4; ++fn)
      #pragma unroll
      for (int q = 0; q < 4; ++q)
        VcS[rg][hi * 4 + q][fn * 16 + r] = acc[fn][q];
  }
  __syncthreads();
  if (kh == 1) {
    #pragma unroll
    for (int fn = 0; fn < 4; ++fn)
      #pragma unroll
      for (int q = 0; q < 4; ++q) {
        float v = VcS[rg][hi * 4 + q][fn * 16 + r] + acc[fn][q];
        Vpart[(size_t)ks * (NPTS * FOUT) + (size_t)(R0 + rg * 16 + hi * 4 + q) * FOUT + fn * 16 + r] = v;
      }
    if (hi == 0) Spart[row_g * 4 + ks] = SpS[rg][0][r] + SpS[rg][1][r];
  }
}

// ---------------- combine partials: divide, ELU ----------------
__global__ __launch_bounds__(256) void k_comb(const float* __restrict__ Vpart,
    const float* __restrict__ Spart, const float* __restrict__ d1v,
    const float* __restrict__ tm, float* __restrict__ out) {
  int gid = blockIdx.x * 256 + threadIdx.x;
  int row = gid >> 6;
  float V = (Vpart[gid] + Vpart[NPTS * FOUT + gid])
          + (Vpart[2 * NPTS * FOUT + gid] + Vpart[3 * NPTS * FOUT + gid]);
  float s = (Spart[row * 4 + 0] + Spart[row * 4 + 1]) + (Spart[row * 4 + 2] + Spart[row * 4 + 3]);
  float a0 = d1v[row * 3 + 0], a1 = d1v[row * 3 + 1], a2 = d1v[row * 3 + 2];
  float M = fmaf(fabsf(a2), tm[2], fmaf(fabsf(a1), tm[1], fabsf(a0) * tm[0]));
  s += 3.f * __expf(-M);
  float o = V / s;
  out[gid] = o > 0.f ? o : expm1f(o);
}

extern "C" void kernel_launch(void* const* d_in, const int* in_sizes, int n_in,
                              void* d_out, int out_size, void* d_ws, size_t ws_size,
                              hipStream_t stream) {
  const float* h  = (const float*)d_in[0];
  const float* W  = (const float*)d_in[2];
  const float* t2 = (const float*)d_in[5];
  float* out = (float*)d_out;

  char* ws = (char*)d_ws;
  __hip_bfloat16* xb = (__hip_bfloat16*)ws;
  float* F = (float*)(ws + (size_t)NPTS * FIN * 2);
  float* sq   = F + 0;                   // 4096
  int*   m1   = (int*)(F + 4096);        // 4096
  float* dkm  = F + 8192;                // 4096
  float* d1v  = F + 16384;               // 12288
  float* Wh   = F + 32768;               // 262144
  float* tmv  = F + 298248;              // 3
  float* Spart = F + 691712;             // 16384
  float* Vpart = F + 708096;             // 1048576
  __hip_bfloat16* WhbT = (__hip_bfloat16*)(F + 1756672); // 131072 floats
  __hip_bfloat16* WbT  = (__hip_bfloat16*)(F + 1887744); // 16384 floats (512x64 bf16)
  float* G = F + 1904128;
  float* bvA    = G + 0;     // 64
  int*   biA    = (int*)(G + 64);
  float* bvB    = G + 128;
  int*   biB    = (int*)(G + 192);
  int*   b1s    = (int*)(G + 256);
  float* tmpart = G + 384;   // 192
  float* kvp    = G + 576;   // 64
  int*   kip    = (int*)(G + 640);
  float* pcA    = G + 704;   // 192 ([c][64])
  float* pcB    = G + 896;   // 192
  float* psA    = G + 1088;  // 98304
  float* psB    = G + 99392; // 98304

  k_prep<<<1026, 256, 0, stream>>>(h, W, xb, sq, m1, WbT);

  #define CARGS(psI, pcI, psO, pcO, goff) \
    h, sq, xb, m1, t2, dkm, bvA, biA, bvB, biB, b1s, tmpart, kvp, kip, \
    psI, pcI, psO, pcO, WbT, Wh, WhbT, goff

  k_carrier<0><<<64 + NG + 32, 512, 0, stream>>>(CARGS(nullptr, nullptr, nullptr, nullptr, 0));
  k_carrier<1><<<64 + NG + 16, 512, 0, stream>>>(CARGS(nullptr, nullptr, nullptr, nullptr, NG));
  k_carrier<2><<<64 + NG, 512, 0, stream>>>(CARGS(nullptr, nullptr, psA, pcA, 2 * NG));
  float* pin = psA; float* cin = pcA; float* pout = psB; float* cout = pcB;
  for (int it = 1; it < 10; ++it) {
    k_carrier<3><<<64 + NG, 512, 0, stream>>>(CARGS(pin, cin, pout, cout, (2 + it) * NG));
    float* tp = pin; pin = pout; pout = tp;
    float* tc = cin; cin = cout; cout = tc;
  }
  k_fin<<<64, 512, 0, stream>>>(h, sq, pin, cin, m1, tmpart, kvp, kip, Wh, d1v, tmv, out);

  k_mainA<<<256, 512, 0, stream>>>(t2, WhbT, d1v, tmv, Vpart, Spart);
  k_comb<<<1024, 256, 0, stream>>>(Vpart, Spart, d1v, tmv, out);
}

// Round 8
// 209.518 us; speedup vs baseline: 1.0978x; 1.0978x over previous
//
#include <hip/hip_runtime.h>
#include <hip/hip_bf16.h>
#include <math.h>

#define NPTS 4096
#define FIN 512
#define FOUT 64
#define NG 88   // gram half-tile units per carrier (12 * 88 = 1056 = 528 tiles * 2)

typedef __attribute__((ext_vector_type(8))) short bf16x8;
typedef __attribute__((ext_vector_type(4))) float f32x4;

static __device__ __forceinline__ unsigned short bfbits(float x) {
  __hip_bfloat16 b = __float2bfloat16(x);
  return *reinterpret_cast<unsigned short*>(&b);
}

static __device__ __forceinline__ float wsum64(float v) {
  #pragma unroll
  for (int mm = 1; mm < 64; mm <<= 1) v += __shfl_xor(v, mm);
  return v;
}

// ---------------- prep: bf16 copy of h, row norms, init m1; blocks>=1024: W -> WbT ----------------
__global__ __launch_bounds__(256) void k_prep(const float* __restrict__ h,
    const float* __restrict__ W, __hip_bfloat16* __restrict__ xb,
    float* __restrict__ sq, int* __restrict__ m1, __hip_bfloat16* __restrict__ WbT) {
  int bid = blockIdx.x, t = threadIdx.x;
  if (bid >= 1024) {
    int base = (bid - 1024) * 16384;
    for (int rep = 0; rep < 64; ++rep) {
      int e = base + rep * 256 + t;
      int n = e >> 9, k = e & 511;
      WbT[e] = __float2bfloat16(W[k * FOUT + n]);
    }
    return;
  }
  int lane = t & 63, wid = t >> 6;
  int row = bid * 4 + wid;
  const float4* hr = (const float4*)(h + (size_t)row * FIN);
  float4 a = hr[lane], b = hr[64 + lane];
  ushort4 pa = { bfbits(a.x), bfbits(a.y), bfbits(a.z), bfbits(a.w) };
  ushort4 pb = { bfbits(b.x), bfbits(b.y), bfbits(b.z), bfbits(b.w) };
  *(ushort4*)(xb + (size_t)row * FIN + 4 * lane) = pa;
  *(ushort4*)(xb + (size_t)row * FIN + 256 + 4 * lane) = pb;
  float s = a.x*a.x + a.y*a.y + a.z*a.z + a.w*a.w
          + b.x*b.x + b.y*b.y + b.z*b.z + b.w*b.w;
  s = wsum64(s);
  if (lane == 0) { sq[row] = s; m1[row] = 0x7F800000; }
}

// ---------------- gram half-tile role: 64 rows x 128 cols, full K ----------------
__device__ __forceinline__ void gram_role2(const __hip_bfloat16* __restrict__ xb,
    const float* __restrict__ sq, int* __restrict__ m1, int gu, char* smem) {
  int tid = threadIdx.x;
  bool act = tid < 256;
  int tile = gu >> 1, half = gu & 1;
  int b = tile, I = 0;
  while (b >= 32 - I) { b -= 32 - I; ++I; }
  int J = I + b;
  char* As = smem;          // 8 KB (64 rows x 128 B)
  char* Bs = smem + 8192;   // 16 KB (128 rows x 128 B)

  int R0 = I * 128 + half * 64, C0 = J * 128;
  int lane = tid & 63, wid4 = (tid >> 6) & 3;
  int rowBase = (wid4 >> 1) * 32;   // 0 / 32
  int colBase = (wid4 & 1) * 64;    // 0 / 64
  int lrow = lane & 15, hi = lane >> 4, rsub = hi * 4;

  f32x4 acc[2][4];
  #pragma unroll
  for (int p = 0; p < 2; ++p)
    #pragma unroll
    for (int q = 0; q < 4; ++q)
      acc[p][q] = (f32x4){0.f, 0.f, 0.f, 0.f};

  int srow = lane >> 3;
  int scol = ((lane & 7) ^ srow) * 8;
  const __hip_bfloat16* gA = xb + (size_t)(R0 + wid4 * 16 + srow) * FIN + scol;
  const __hip_bfloat16* gB = xb + (size_t)(C0 + wid4 * 32 + srow) * FIN + scol;
  char* lA = As + wid4 * 2048;
  char* lB = Bs + wid4 * 4096;
  int rdswz = (lrow & 7) << 4;

  for (int kt = 0; kt < 8; ++kt) {
    int K0 = kt * 64;
    if (act) {
      #pragma unroll
      for (int j = 0; j < 2; ++j)
        __builtin_amdgcn_global_load_lds(
            (const __attribute__((address_space(1))) unsigned int*)(gA + (size_t)(8 * j) * FIN + K0),
            (__attribute__((address_space(3))) unsigned int*)(lA + j * 1024), 16, 0, 0);
      #pragma unroll
      for (int j = 0; j < 4; ++j)
        __builtin_amdgcn_global_load_lds(
            (const __attribute__((address_space(1))) unsigned int*)(gB + (size_t)(8 * j) * FIN + K0),
            (__attribute__((address_space(3))) unsigned int*)(lB + j * 1024), 16, 0, 0);
    }
    __syncthreads();
    if (act) {
      #pragma unroll
      for (int s = 0; s < 2; ++s) {
        int k0b = s * 64;
        bf16x8 av[2], bw[4];
        #pragma unroll
        for (int f = 0; f < 2; ++f)
          av[f] = *(const bf16x8*)(As + (rowBase + f * 16 + lrow) * 128 + ((k0b + hi * 16) ^ rdswz));
        #pragma unroll
        for (int f = 0; f < 4; ++f)
          bw[f] = *(const bf16x8*)(Bs + (colBase + f * 16 + lrow) * 128 + ((k0b + hi * 16) ^ rdswz));
        #pragma unroll
        for (int fi = 0; fi < 2; ++fi)
          #pragma unroll
          for (int fj = 0; fj < 4; ++fj)
            acc[fi][fj] = __builtin_amdgcn_mfma_f32_16x16x32_bf16(av[fi], bw[fj], acc[fi][fj], 0, 0, 0);
      }
    }
    __syncthreads();
  }
  if (!act) return;

  int rowBaseG = R0 + rowBase, colBaseG = C0 + colBase;
  float sqr[8], sqc4[4];
  #pragma unroll
  for (int fi = 0; fi < 2; ++fi)
    #pragma unroll
    for (int rg = 0; rg < 4; ++rg)
      sqr[fi * 4 + rg] = sq[rowBaseG + fi * 16 + rsub + rg];
  #pragma unroll
  for (int fj = 0; fj < 4; ++fj) sqc4[fj] = sq[colBaseG + fj * 16 + lrow];

  float rmin[8], cmin[4];
  #pragma unroll
  for (int q = 0; q < 8; ++q) rmin[q] = INFINITY;
  #pragma unroll
  for (int q = 0; q < 4; ++q) cmin[q] = INFINITY;

  #pragma unroll
  for (int fi = 0; fi < 2; ++fi)
    #pragma unroll
    for (int fj = 0; fj < 4; ++fj)
      #pragma unroll
      for (int rg = 0; rg < 4; ++rg) {
        int r = rowBaseG + fi * 16 + rsub + rg;
        int c = colBaseG + fj * 16 + lrow;
        float d2 = sqr[fi * 4 + rg] + sqc4[fj] - 2.f * acc[fi][fj][rg];
        if (r == c) d2 = INFINITY;
        rmin[fi * 4 + rg] = fminf(rmin[fi * 4 + rg], d2);
        cmin[fj] = fminf(cmin[fj], d2);
      }

  #pragma unroll
  for (int mm = 1; mm < 16; mm <<= 1) {
    #pragma unroll
    for (int q = 0; q < 8; ++q) rmin[q] = fminf(rmin[q], __shfl_xor(rmin[q], mm));
  }
  if ((lane & 15) == 0) {
    #pragma unroll
    for (int q = 0; q < 8; ++q) {
      int r = rowBaseG + (q >> 2) * 16 + rsub + (q & 3);
      atomicMin(&m1[r], __float_as_int(rmin[q]));
    }
  }
  if (I != J) {
    #pragma unroll
    for (int mm = 16; mm < 64; mm <<= 1) {
      #pragma unroll
      for (int q = 0; q < 4; ++q) cmin[q] = fminf(cmin[q], __shfl_xor(cmin[q], mm));
    }
    if ((lane >> 4) == 0) {
      #pragma unroll
      for (int q = 0; q < 4; ++q)
        atomicMin(&m1[colBaseG + q * 16 + lane], __float_as_int(cmin[q]));
    }
  }
}

// ---------------- Wh = xb @ WbT^T via MFMA ----------------
__device__ __forceinline__ void whmm_role(const __hip_bfloat16* __restrict__ xb,
    const __hip_bfloat16* __restrict__ WbT, float* __restrict__ Wh, int wb) {
  int t = threadIdx.x, lane = t & 63, wid = t >> 6;
  int r16 = lane & 15, hi = lane >> 4;
  int rbase = wb * 128 + wid * 16;
  f32x4 acc[4];
  #pragma unroll
  for (int fn = 0; fn < 4; ++fn) acc[fn] = (f32x4){0.f, 0.f, 0.f, 0.f};
  const __hip_bfloat16* aP = xb + (size_t)(rbase + r16) * FIN + hi * 8;
  const __hip_bfloat16* bP[4];
  #pragma unroll
  for (int fn = 0; fn < 4; ++fn)
    bP[fn] = WbT + (size_t)(fn * 16 + r16) * FIN + hi * 8;
  #pragma unroll
  for (int kk = 0; kk < 16; ++kk) {
    bf16x8 a = *(const bf16x8*)(aP + kk * 32);
    #pragma unroll
    for (int fn = 0; fn < 4; ++fn) {
      bf16x8 bw = *(const bf16x8*)(bP[fn] + kk * 32);
      acc[fn] = __builtin_amdgcn_mfma_f32_16x16x32_bf16(a, bw, acc[fn], 0, 0, 0);
    }
  }
  #pragma unroll
  for (int fn = 0; fn < 4; ++fn)
    #pragma unroll
    for (int q = 0; q < 4; ++q)
      Wh[(size_t)(rbase + hi * 4 + q) * FOUT + fn * 16 + r16] = acc[fn][q];
}

// ---------------- transpose Wh -> WhbT role ----------------
__device__ __forceinline__ void tr_role(const float* __restrict__ Wh,
    __hip_bfloat16* __restrict__ WhbT, int trb, char* smem) {
  __hip_bfloat16 (*tT)[264] = (__hip_bfloat16(*)[264])smem;
  int t = threadIdx.x;
  bool act = t < 256;
  int kbase = trb * 256;
  if (act) {
    for (int rep = 0; rep < 64; ++rep) {
      int idx = t + rep * 256;
      int k = idx >> 6, n = idx & 63;
      tT[n][k] = __float2bfloat16(Wh[(size_t)(kbase + k) * FOUT + n]);
    }
  }
  __syncthreads();
  if (act) {
    int n = t >> 2, kq = t & 3;
    #pragma unroll
    for (int rep = 0; rep < 8; ++rep) {
      int kk = kq * 64 + rep * 8;
      bf16x8 v = *(const bf16x8*)&tT[n][kk];
      *(bf16x8*)(WhbT + (size_t)n * NPTS + kbase + kk) = v;
    }
  }
}

// ---------------- row loader ----------------
__device__ __forceinline__ void load_rows(const float* __restrict__ h, int rbase,
    int lane, float x[8][8]) {
  #pragma unroll
  for (int r = 0; r < 8; ++r) {
    const float4* xr = (const float4*)(h + (size_t)(rbase + r) * FIN);
    float4 u0 = xr[2 * lane], u1 = xr[2 * lane + 1];
    x[r][0]=u0.x; x[r][1]=u0.y; x[r][2]=u0.z; x[r][3]=u0.w;
    x[r][4]=u1.x; x[r][5]=u1.y; x[r][6]=u1.z; x[r][7]=u1.w;
  }
}

// ---------------- Lloyd assign ----------------
__device__ __forceinline__ void lloyd_assign(const float* __restrict__ h,
    const float* __restrict__ sq, const float* cents, float* wsum, float* wcnt,
    float* __restrict__ psOut, float* __restrict__ pcOut) {
  int t = threadIdx.x, lane = t & 63, wid = t >> 6, b = blockIdx.x;
  float c0r[8], c1r[8], c2r[8];
  {
    float4 u;
    u = *(const float4*)&cents[8 * lane];          c0r[0]=u.x;c0r[1]=u.y;c0r[2]=u.z;c0r[3]=u.w;
    u = *(const float4*)&cents[8 * lane + 4];      c0r[4]=u.x;c0r[5]=u.y;c0r[6]=u.z;c0r[7]=u.w;
    u = *(const float4*)&cents[512 + 8 * lane];    c1r[0]=u.x;c1r[1]=u.y;c1r[2]=u.z;c1r[3]=u.w;
    u = *(const float4*)&cents[512 + 8 * lane + 4];c1r[4]=u.x;c1r[5]=u.y;c1r[6]=u.z;c1r[7]=u.w;
    u = *(const float4*)&cents[1024 + 8 * lane];   c2r[0]=u.x;c2r[1]=u.y;c2r[2]=u.z;c2r[3]=u.w;
    u = *(const float4*)&cents[1024 + 8*lane + 4]; c2r[4]=u.x;c2r[5]=u.y;c2r[6]=u.z;c2r[7]=u.w;
  }
  float s0 = 0.f, s1 = 0.f, s2 = 0.f;
  #pragma unroll
  for (int q = 0; q < 8; ++q) {
    s0 = fmaf(c0r[q], c0r[q], s0); s1 = fmaf(c1r[q], c1r[q], s1); s2 = fmaf(c2r[q], c2r[q], s2);
  }
  #pragma unroll
  for (int mm = 1; mm < 64; mm <<= 1) {
    s0 += __shfl_xor(s0, mm); s1 += __shfl_xor(s1, mm); s2 += __shfl_xor(s2, mm);
  }
  float sqc0 = s0, sqc1 = s1, sqc2 = s2;

  int rbase = b * 64 + wid * 8;
  float x[8][8];
  load_rows(h, rbase, lane, x);
  float d[8][3];
  #pragma unroll
  for (int r = 0; r < 8; ++r) { d[r][0] = 0.f; d[r][1] = 0.f; d[r][2] = 0.f; }
  #pragma unroll
  for (int r = 0; r < 8; ++r)
    #pragma unroll
    for (int q = 0; q < 8; ++q) {
      d[r][0] = fmaf(x[r][q], c0r[q], d[r][0]);
      d[r][1] = fmaf(x[r][q], c1r[q], d[r][1]);
      d[r][2] = fmaf(x[r][q], c2r[q], d[r][2]);
    }
  #pragma unroll
  for (int mm = 1; mm < 64; mm <<= 1) {
    #pragma unroll
    for (int r = 0; r < 8; ++r) {
      d[r][0] += __shfl_xor(d[r][0], mm);
      d[r][1] += __shfl_xor(d[r][1], mm);
      d[r][2] += __shfl_xor(d[r][2], mm);
    }
  }
  float ps[3][8];
  #pragma unroll
  for (int c = 0; c < 3; ++c)
    #pragma unroll
    for (int q = 0; q < 8; ++q) ps[c][q] = 0.f;
  float cnt0 = 0.f, cnt1 = 0.f, cnt2 = 0.f;
  #pragma unroll
  for (int r = 0; r < 8; ++r) {
    float sr = sq[rbase + r];
    float e0 = sr + sqc0 - 2.f * d[r][0];
    float e1 = sr + sqc1 - 2.f * d[r][1];
    float e2 = sr + sqc2 - 2.f * d[r][2];
    int bc = 0; float bd = e0;
    if (e1 < bd) { bd = e1; bc = 1; }
    if (e2 < bd) { bd = e2; bc = 2; }
    float f0 = bc == 0 ? 1.f : 0.f, f1 = bc == 1 ? 1.f : 0.f, f2 = bc == 2 ? 1.f : 0.f;
    #pragma unroll
    for (int q = 0; q < 8; ++q) {
      ps[0][q] = fmaf(f0, x[r][q], ps[0][q]);
      ps[1][q] = fmaf(f1, x[r][q], ps[1][q]);
      ps[2][q] = fmaf(f2, x[r][q], ps[2][q]);
    }
    cnt0 += f0; cnt1 += f1; cnt2 += f2;
  }
  #pragma unroll
  for (int c = 0; c < 3; ++c) {
    *(float4*)&wsum[wid * 1536 + c * 512 + 8 * lane]     = make_float4(ps[c][0], ps[c][1], ps[c][2], ps[c][3]);
    *(float4*)&wsum[wid * 1536 + c * 512 + 8 * lane + 4] = make_float4(ps[c][4], ps[c][5], ps[c][6], ps[c][7]);
  }
  if (lane == 0) { wcnt[wid * 3 + 0] = cnt0; wcnt[wid * 3 + 1] = cnt1; wcnt[wid * 3 + 2] = cnt2; }
  __syncthreads();
  for (int idx = t; idx < 1536; idx += 512) {
    float s = ((wsum[0 * 1536 + idx] + wsum[1 * 1536 + idx]) + (wsum[2 * 1536 + idx] + wsum[3 * 1536 + idx]))
            + ((wsum[4 * 1536 + idx] + wsum[5 * 1536 + idx]) + (wsum[6 * 1536 + idx] + wsum[7 * 1536 + idx]));
    psOut[(size_t)b * 1536 + idx] = s;
  }
  if (t < 3) {
    float s = 0.f;
    for (int w = 0; w < 8; ++w) s += wcnt[w * 3 + t];
    pcOut[t * 64 + b] = s;
  }
}

// ---------------- carrier: kmeans (blocks 0-63) + gram halves + tail roles ----------------
template<int MODE>
__global__ __launch_bounds__(512) void k_carrier(
    const float* __restrict__ h, const float* __restrict__ sq,
    const __hip_bfloat16* __restrict__ xb, int* __restrict__ m1,
    const float* __restrict__ t2, float* __restrict__ dkm,
    float* __restrict__ bvA, int* __restrict__ biA,
    float* __restrict__ bvB, int* __restrict__ biB, int* __restrict__ b1s,
    float* __restrict__ tmpart, float* __restrict__ kvp, int* __restrict__ kip,
    const float* __restrict__ psIn, const float* __restrict__ pcIn,
    float* __restrict__ psOut, float* __restrict__ pcOut,
    const __hip_bfloat16* __restrict__ WbT, float* __restrict__ Wh,
    __hip_bfloat16* __restrict__ WhbT, int gramOff) {
  __shared__ __align__(16) char smem[55552];
  int bid = blockIdx.x;
  if (bid >= 64 + NG) {
    if (MODE == 0) whmm_role(xb, WbT, Wh, bid - 64 - NG);
    else           tr_role(Wh, WhbT, bid - 64 - NG, smem);
    return;
  }
  if (bid >= 64) { gram_role2(xb, sq, m1, gramOff + bid - 64, smem); return; }

  float* wsum  = (float*)smem;
  float* cents = (float*)(smem + 49152);
  float* wcnt  = (float*)(smem + 55296);
  float* misc  = (float*)(smem + 55392);
  float* rv = misc;
  int*   ri = (int*)(misc + 8);
  int*   sI = (int*)(misc + 16);
  float* cntS = misc + 20;

  int t = threadIdx.x, lane = t & 63, wid = t >> 6, b = bid;

  if (MODE <= 1) {
    float cr[8];
    int b1 = 0;
    if (MODE == 1) {
      if (wid == 0) {
        float v = bvA[lane]; int i = biA[lane];
        #pragma unroll
        for (int mm = 1; mm < 64; mm <<= 1) {
          float ov = __shfl_xor(v, mm); int oi = __shfl_xor(i, mm);
          if (ov > v || (ov == v && oi < i)) { v = ov; i = oi; }
        }
        if (lane == 0) sI[0] = i;
      }
      __syncthreads();
      b1 = sI[0];
      if (b == 0 && t == 0) b1s[0] = b1;
    }
    {
      const float4* cp = (const float4*)(h + (MODE == 0 ? 0 : (size_t)b1 * FIN));
      float4 u0 = cp[2 * lane], u1 = cp[2 * lane + 1];
      cr[0]=u0.x;cr[1]=u0.y;cr[2]=u0.z;cr[3]=u0.w;cr[4]=u1.x;cr[5]=u1.y;cr[6]=u1.z;cr[7]=u1.w;
    }
    float s0 = 0.f;
    #pragma unroll
    for (int q = 0; q < 8; ++q) s0 = fmaf(cr[q], cr[q], s0);
    float sqc0 = wsum64(s0);
    int rbase = b * 64 + wid * 8;
    float x[8][8];
    load_rows(h, rbase, lane, x);
    float dd[8];
    #pragma unroll
    for (int r = 0; r < 8; ++r) dd[r] = 0.f;
    #pragma unroll
    for (int r = 0; r < 8; ++r)
      #pragma unroll
      for (int q = 0; q < 8; ++q) dd[r] = fmaf(x[r][q], cr[q], dd[r]);
    #pragma unroll
    for (int mm = 1; mm < 64; mm <<= 1) {
      #pragma unroll
      for (int r = 0; r < 8; ++r) dd[r] += __shfl_xor(dd[r], mm);
    }
    float bv = -1.f; int bi = 0;
    #pragma unroll
    for (int r = 0; r < 8; ++r) {
      int row = rbase + r;
      float d = sq[row] + sqc0 - 2.f * dd[r];
      if (MODE == 1) d = fminf(d, dkm[row]);
      if (lane == 0) dkm[row] = d;
      if (d > bv) { bv = d; bi = row; }
    }
    if (lane == 0) { rv[wid] = bv; ri[wid] = bi; }
    if (MODE == 0) {
      if (wid == 1) {
        #pragma unroll
        for (int c = 0; c < 3; ++c) {
          float m = fabsf(t2[c * NPTS + b * 64 + lane]);
          #pragma unroll
          for (int mm = 1; mm < 64; mm <<= 1) m = fmaxf(m, __shfl_xor(m, mm));
          if (lane == 0) tmpart[b * 3 + c] = m;
        }
      } else if (wid == 2) {
        int k = b * 64 + lane;
        float v = t2[k] + t2[NPTS + k] + t2[2 * NPTS + k];
        int ki = k;
        #pragma unroll
        for (int mm = 1; mm < 64; mm <<= 1) {
          float ov = __shfl_xor(v, mm); int oi = __shfl_xor(ki, mm);
          if (ov < v || (ov == v && oi < ki)) { v = ov; ki = oi; }
        }
        if (lane == 0) { kvp[b] = v; kip[b] = ki; }
      }
    }
    __syncthreads();
    if (t == 0) {
      float vv = rv[0]; int ii = ri[0];
      for (int w = 1; w < 8; ++w)
        if (rv[w] > vv || (rv[w] == vv && ri[w] < ii)) { vv = rv[w]; ii = ri[w]; }
      if (MODE == 0) { bvA[b] = vv; biA[b] = ii; }
      else           { bvB[b] = vv; biB[b] = ii; }
    }
    return;
  }

  if (MODE == 2) {
    if (wid == 0) {
      float v = bvB[lane]; int i = biB[lane];
      #pragma unroll
      for (int mm = 1; mm < 64; mm <<= 1) {
        float ov = __shfl_xor(v, mm); int oi = __shfl_xor(i, mm);
        if (ov > v || (ov == v && oi < i)) { v = ov; i = oi; }
      }
      if (lane == 0) sI[0] = i;
    }
    __syncthreads();
    int b1 = b1s[0], b2 = sI[0];
    cents[t]        = h[t];
    cents[512 + t]  = h[(size_t)b1 * FIN + t];
    cents[1024 + t] = h[(size_t)b2 * FIN + t];
    __syncthreads();
    lloyd_assign(h, sq, cents, wsum, wcnt, psOut, pcOut);
    return;
  }

  // MODE 3
  if (t < 192) {
    float v = pcIn[t];
    v = wsum64(v);
    if ((t & 63) == 0) cntS[t >> 6] = v;
  }
  __syncthreads();
  if (t < 384) {
    const f32x4* P = (const f32x4*)psIn;
    f32x4 a0 = {0,0,0,0}, a1 = {0,0,0,0}, a2 = {0,0,0,0}, a3 = {0,0,0,0};
    #pragma unroll 4
    for (int bq = 0; bq < 64; bq += 4) {
      a0 += P[(bq + 0) * 384 + t];
      a1 += P[(bq + 1) * 384 + t];
      a2 += P[(bq + 2) * 384 + t];
      a3 += P[(bq + 3) * 384 + t];
    }
    f32x4 s = (a0 + a1) + (a2 + a3);
    float cden = fmaxf(cntS[t >> 7], 1.f);
    f32x4 res;
    res[0] = s[0] / cden; res[1] = s[1] / cden; res[2] = s[2] / cden; res[3] = s[3] / cden;
    *(f32x4*)&cents[4 * t] = res;
  }
  __syncthreads();
  lloyd_assign(h, sq, cents, wsum, wcnt, psOut, pcOut);
}

// ---------------- finalize: centers, dc (from m1), d1val, tm/kstar tail ----------------
__global__ __launch_bounds__(512) void k_fin(const float* __restrict__ h,
    const float* __restrict__ sq, const float* __restrict__ psIn, const float* __restrict__ pcIn,
    const int* __restrict__ m1, const float* __restrict__ tmpart,
    const float* __restrict__ kvp, const int* __restrict__ kip,
    const float* __restrict__ Wh, float* __restrict__ d1v,
    float* __restrict__ tmv, float* __restrict__ out) {
  __shared__ float cents[1536];
  __shared__ float cntS[3];
  __shared__ float dcw[8];
  __shared__ int skstar;
  int t = threadIdx.x, lane = t & 63, wid = t >> 6, b = blockIdx.x;
  {
    float sdc = 0.f;
    #pragma unroll
    for (int q = 0; q < 8; ++q)
      sdc += sqrtf(fmaxf(__int_as_float(m1[t + 512 * q]), 0.f));
    sdc = wsum64(sdc);
    if (lane == 0) dcw[wid] = sdc;
  }
  if (t < 192) {
    float v = pcIn[t];
    v = wsum64(v);
    if ((t & 63) == 0) cntS[t >> 6] = v;
  }
  __syncthreads();
  if (t < 384) {
    const f32x4* P = (const f32x4*)psIn;
    f32x4 a0 = {0,0,0,0}, a1 = {0,0,0,0}, a2 = {0,0,0,0}, a3 = {0,0,0,0};
    #pragma unroll 4
    for (int bq = 0; bq < 64; bq += 4) {
      a0 += P[(bq + 0) * 384 + t];
      a1 += P[(bq + 1) * 384 + t];
      a2 += P[(bq + 2) * 384 + t];
      a3 += P[(bq + 3) * 384 + t];
    }
    f32x4 s = (a0 + a1) + (a2 + a3);
    float cden = fmaxf(cntS[t >> 7], 1.f);
    f32x4 res;
    res[0] = s[0] / cden; res[1] = s[1] / cden; res[2] = s[2] / cden; res[3] = s[3] / cden;
    *(f32x4*)&cents[4 * t] = res;
  }
  __syncthreads();
  float dcv = (((dcw[0] + dcw[1]) + (dcw[2] + dcw[3])) + ((dcw[4] + dcw[5]) + (dcw[6] + dcw[7])))
            * (1.f / (float)NPTS);
  float c0r[8], c1r[8], c2r[8];
  {
    float4 u;
    u = *(const float4*)&cents[8 * lane];          c0r[0]=u.x;c0r[1]=u.y;c0r[2]=u.z;c0r[3]=u.w;
    u = *(const float4*)&cents[8 * lane + 4];      c0r[4]=u.x;c0r[5]=u.y;c0r[6]=u.z;c0r[7]=u.w;
    u = *(const float4*)&cents[512 + 8 * lane];    c1r[0]=u.x;c1r[1]=u.y;c1r[2]=u.z;c1r[3]=u.w;
    u = *(const float4*)&cents[512 + 8 * lane + 4];c1r[4]=u.x;c1r[5]=u.y;c1r[6]=u.z;c1r[7]=u.w;
    u = *(const float4*)&cents[1024 + 8 * lane];   c2r[0]=u.x;c2r[1]=u.y;c2r[2]=u.z;c2r[3]=u.w;
    u = *(const float4*)&cents[1024 + 8*lane + 4]; c2r[4]=u.x;c2r[5]=u.y;c2r[6]=u.z;c2r[7]=u.w;
  }
  float s0 = 0.f, s1 = 0.f, s2 = 0.f;
  #pragma unroll
  for (int q = 0; q < 8; ++q) {
    s0 = fmaf(c0r[q], c0r[q], s0); s1 = fmaf(c1r[q], c1r[q], s1); s2 = fmaf(c2r[q], c2r[q], s2);
  }
  #pragma unroll
  for (int mm = 1; mm < 64; mm <<= 1) {
    s0 += __shfl_xor(s0, mm); s1 += __shfl_xor(s1, mm); s2 += __shfl_xor(s2, mm);
  }
  float sqc0 = s0, sqc1 = s1, sqc2 = s2;

  int rbase = b * 64 + wid * 8;
  float x[8][8];
  load_rows(h, rbase, lane, x);
  float d[8][3];
  #pragma unroll
  for (int r = 0; r < 8; ++r) { d[r][0] = 0.f; d[r][1] = 0.f; d[r][2] = 0.f; }
  #pragma unroll
  for (int r = 0; r < 8; ++r)
    #pragma unroll
    for (int q = 0; q < 8; ++q) {
      d[r][0] = fmaf(x[r][q], c0r[q], d[r][0]);
      d[r][1] = fmaf(x[r][q], c1r[q], d[r][1]);
      d[r][2] = fmaf(x[r][q], c2r[q], d[r][2]);
    }
  #pragma unroll
  for (int mm = 1; mm < 64; mm <<= 1) {
    #pragma unroll
    for (int r = 0; r < 8; ++r) {
      d[r][0] += __shfl_xor(d[r][0], mm);
      d[r][1] += __shfl_xor(d[r][1], mm);
      d[r][2] += __shfl_xor(d[r][2], mm);
    }
  }
  if (lane == 0) {
    #pragma unroll
    for (int r = 0; r < 8; ++r) {
      int row = rbase + r;
      float sr = sq[row];
      float q0 = sqrtf(fmaxf(sr + sqc0 - 2.f * d[r][0], 0.f));
      float q1 = sqrtf(fmaxf(sr + sqc1 - 2.f * d[r][1], 0.f));
      float q2 = sqrtf(fmaxf(sr + sqc2 - 2.f * d[r][2], 0.f));
      float nr = q1;
      d1v[row * 3 + 0] = (q0 != 0.f) ? (dcv * nr / (q0 * q0)) : 0.f;
      d1v[row * 3 + 1] = (q1 != 0.f) ? (dcv * nr / (q1 * q1)) : 0.f;
      d1v[row * 3 + 2] = (q2 != 0.f) ? (dcv * nr / (q2 * q2)) : 0.f;
    }
  }
  if (b == 0) {
    if (t < 3) {
      float m = 0.f;
      for (int q = 0; q < 64; ++q) m = fmaxf(m, tmpart[q * 3 + t]);
      tmv[t] = m;
    }
    if (wid == 0) {
      float v = kvp[lane]; int i = kip[lane];
      #pragma unroll
      for (int mm = 1; mm < 64; mm <<= 1) {
        float ov = __shfl_xor(v, mm); int oi = __shfl_xor(i, mm);
        if (ov < v || (ov == v && oi < i)) { v = ov; i = oi; }
      }
      if (lane == 0) skstar = i;
    }
    __syncthreads();
    int kstar = skstar;
    if (t < 192) {
      int c = t >> 6, j = t & 63;
      float wv = Wh[(size_t)kstar * FOUT + j];
      out[(size_t)(NPTS + c) * FOUT + j] = wv > 0.f ? wv : expm1f(wv);
    }
  }
}

// ---------------- fused softmax @ Wh, full K per block, direct output ----------------
__global__ __launch_bounds__(512) void k_mainB(const float* __restrict__ t2,
    const __hip_bfloat16* __restrict__ WhbT, const float* __restrict__ d1v,
    const float* __restrict__ tm, float* __restrict__ out) {
  __shared__ float t2s[3 * 4096];     // 48 KB
  __shared__ float VcS[8][16][68];    // ~34.8 KB
  __shared__ float SpS[8][16];
  __shared__ float Mrow[16];
  int t = threadIdx.x, lane = t & 63, wid = t >> 6;
  int R0 = blockIdx.x * 16;
  for (int idx = t; idx < 3072; idx += 512)
    ((f32x4*)t2s)[idx] = ((const f32x4*)t2)[idx];
  __syncthreads();
  int r16 = lane & 15, hi = lane >> 4;
  int row_g = R0 + r16;
  float a0 = d1v[row_g * 3 + 0], a1 = d1v[row_g * 3 + 1], a2 = d1v[row_g * 3 + 2];
  float M = fmaf(fabsf(a2), tm[2], fmaf(fabsf(a1), tm[1], fabsf(a0) * tm[0]));
  if (wid == 0 && hi == 0) Mrow[r16] = M;
  int K0 = wid * 512;
  f32x4 acc[4];
  #pragma unroll
  for (int fn = 0; fn < 4; ++fn) acc[fn] = (f32x4){0.f, 0.f, 0.f, 0.f};
  float Sp = 0.f;
  const __hip_bfloat16* bwB[4];
  #pragma unroll
  for (int fn = 0; fn < 4; ++fn)
    bwB[fn] = WhbT + (size_t)(fn * 16 + r16) * NPTS + K0 + hi * 8;

  for (int kst = 0; kst < 16; ++kst) {
    int kb = K0 + kst * 32 + hi * 8;
    f32x4 c0a = *(const f32x4*)&t2s[kb],        c0b = *(const f32x4*)&t2s[kb + 4];
    f32x4 c1a = *(const f32x4*)&t2s[4096 + kb], c1b = *(const f32x4*)&t2s[4096 + kb + 4];
    f32x4 c2a = *(const f32x4*)&t2s[8192 + kb], c2b = *(const f32x4*)&t2s[8192 + kb + 4];
    float pv[8];
    #pragma unroll
    for (int j = 0; j < 4; ++j) {
      float L  = fmaf(a0, c0a[j], fmaf(a1, c1a[j], fmaf(a2, c2a[j], -M)));
      pv[j] = __expf(L);
      float L2 = fmaf(a0, c0b[j], fmaf(a1, c1b[j], fmaf(a2, c2b[j], -M)));
      pv[4 + j] = __expf(L2);
    }
    Sp += ((pv[0] + pv[1]) + (pv[2] + pv[3])) + ((pv[4] + pv[5]) + (pv[6] + pv[7]));
    union { bf16x8 v; __hip_bfloat162 h2[4]; } pa;
    #pragma unroll
    for (int jj = 0; jj < 4; ++jj) {
      float2 f2; f2.x = pv[2 * jj]; f2.y = pv[2 * jj + 1];
      pa.h2[jj] = __float22bfloat162_rn(f2);
    }
    #pragma unroll
    for (int fn = 0; fn < 4; ++fn) {
      bf16x8 bw = *(const bf16x8*)(bwB[fn] + kst * 32);
      acc[fn] = __builtin_amdgcn_mfma_f32_16x16x32_bf16(pa.v, bw, acc[fn], 0, 0, 0);
    }
  }
  Sp += __shfl_xor(Sp, 16);
  Sp += __shfl_xor(Sp, 32);
  if (hi == 0) SpS[wid][r16] = Sp;
  #pragma unroll
  for (int fn = 0; fn < 4; ++fn)
    #pragma unroll
    for (int q = 0; q < 4; ++q)
      VcS[wid][hi * 4 + q][fn * 16 + r16] = acc[fn][q];
  __syncthreads();
  for (int e = t; e < 1024; e += 512) {
    int row = e >> 6, col = e & 63;
    float V = 0.f;
    #pragma unroll
    for (int w = 0; w < 8; ++w) V += VcS[w][row][col];
    float S = 3.f * __expf(-Mrow[row]);
    #pragma unroll
    for (int w = 0; w < 8; ++w) S += SpS[w][row];
    float o = V / S;
    out[(size_t)(R0 + row) * FOUT + col] = o > 0.f ? o : expm1f(o);
  }
}

extern "C" void kernel_launch(void* const* d_in, const int* in_sizes, int n_in,
                              void* d_out, int out_size, void* d_ws, size_t ws_size,
                              hipStream_t stream) {
  const float* h  = (const float*)d_in[0];
  const float* W  = (const float*)d_in[2];
  const float* t2 = (const float*)d_in[5];
  float* out = (float*)d_out;

  char* ws = (char*)d_ws;
  __hip_bfloat16* xb = (__hip_bfloat16*)ws;
  float* F = (float*)(ws + (size_t)NPTS * FIN * 2);
  float* sq   = F + 0;
  int*   m1   = (int*)(F + 4096);
  float* dkm  = F + 8192;
  float* d1v  = F + 16384;
  float* Wh   = F + 32768;
  float* tmv  = F + 298248;
  __hip_bfloat16* WhbT = (__hip_bfloat16*)(F + 1756672);
  __hip_bfloat16* WbT  = (__hip_bfloat16*)(F + 1887744);
  float* G = F + 1904128;
  float* bvA    = G + 0;
  int*   biA    = (int*)(G + 64);
  float* bvB    = G + 128;
  int*   biB    = (int*)(G + 192);
  int*   b1s    = (int*)(G + 256);
  float* tmpart = G + 384;
  float* kvp    = G + 576;
  int*   kip    = (int*)(G + 640);
  float* pcA    = G + 704;
  float* pcB    = G + 896;
  float* psA    = G + 1088;
  float* psB    = G + 99392;

  k_prep<<<1026, 256, 0, stream>>>(h, W, xb, sq, m1, WbT);

  #define CARGS(psI, pcI, psO, pcO, goff) \
    h, sq, xb, m1, t2, dkm, bvA, biA, bvB, biB, b1s, tmpart, kvp, kip, \
    psI, pcI, psO, pcO, WbT, Wh, WhbT, goff

  k_carrier<0><<<64 + NG + 32, 512, 0, stream>>>(CARGS(nullptr, nullptr, nullptr, nullptr, 0));
  k_carrier<1><<<64 + NG + 16, 512, 0, stream>>>(CARGS(nullptr, nullptr, nullptr, nullptr, NG));
  k_carrier<2><<<64 + NG, 512, 0, stream>>>(CARGS(nullptr, nullptr, psA, pcA, 2 * NG));
  float* pin = psA; float* cin = pcA; float* pout = psB; float* cout = pcB;
  for (int it = 1; it < 10; ++it) {
    k_carrier<3><<<64 + NG, 512, 0, stream>>>(CARGS(pin, cin, pout, cout, (2 + it) * NG));
    float* tp = pin; pin = pout; pout = tp;
    float* tc = cin; cin = cout; cout = tc;
  }
  k_fin<<<64, 512, 0, stream>>>(h, sq, pin, cin, m1, tmpart, kvp, kip, Wh, d1v, tmv, out);

  k_mainB<<<256, 512, 0, stream>>>(t2, WhbT, d1v, tmv, out);
}